// Round 6
// baseline (253.373 us; speedup 1.0000x reference)
//
#include <hip/hip_runtime.h>
#include <hip/hip_bf16.h>

typedef __attribute__((ext_vector_type(8))) short short8;
typedef __attribute__((ext_vector_type(4))) short short4v;
typedef __attribute__((ext_vector_type(4))) float f32x4;

#define B_  2
#define S_  2048
#define H_  16
#define HD_ 64
#define D_  1024
#define QSCALE 0.18033688f   /* 0.125 * log2(e): folds softmax exp2 conversion into Q proj */

__device__ __forceinline__ short f2bs(float f) {
  union { float f; unsigned u; } c; c.f = f;
  unsigned u = c.u;
  u += 0x7fffu + ((u >> 16) & 1u);   // RNE; inputs are never NaN
  return (short)(u >> 16);
}

__device__ __forceinline__ float bs2f(short v) {
  union { unsigned u; float f; } c;
  c.u = ((unsigned)(unsigned short)v) << 16;
  return c.f;
}

__device__ __forceinline__ unsigned pack_bf16(float a, float b) {
  __hip_bfloat162 h = __float22bfloat162_rn(float2{a, b});   // v_cvt_pk_bf16_f32
  return *reinterpret_cast<unsigned*>(&h);
}

__device__ __forceinline__ float fexp2(float x) {
#if __has_builtin(__builtin_amdgcn_exp2f)
  return __builtin_amdgcn_exp2f(x);
#else
  return exp2f(x);
#endif
}

__device__ __forceinline__ float frcp(float x) {
#if __has_builtin(__builtin_amdgcn_rcpf)
  return __builtin_amdgcn_rcpf(x);
#else
  return 1.0f / x;
#endif
}

#define GL2LDS(gp, lp) __builtin_amdgcn_global_load_lds( \
    (const __attribute__((address_space(1))) unsigned int*)(gp), \
    (__attribute__((address_space(3))) unsigned int*)(lp), 16, 0, 0)

// ---------------- fused prep: x/y convert + weight transposes + counter zero ----------------
__global__ __launch_bounds__(256)
void prep_kernel(const float* __restrict__ x, const float* __restrict__ y,
                 short* __restrict__ xb, short* __restrict__ yb,
                 const float* __restrict__ Wkv, short* __restrict__ Wkvt,
                 const float* __restrict__ Wq, short* __restrict__ Wqt,
                 const float* __restrict__ Wo, short* __restrict__ Wot,
                 int* __restrict__ cnt) {
  __shared__ float tile[64][65];
  int bx = blockIdx.x;
  if (bx < 8192) {
    if (bx == 0) cnt[threadIdx.x] = 0;          // zero split-K counters (256 groups)
    int i = bx * 256 + threadIdx.x;
    const float4* src; short4v* dst; int j;
    if (i < (1 << 20)) { src = (const float4*)x; dst = (short4v*)xb; j = i; }
    else               { src = (const float4*)y; dst = (short4v*)yb; j = i - (1 << 20); }
    float4 f = src[j];
    short4v o;
    o.x = f2bs(f.x); o.y = f2bs(f.y); o.z = f2bs(f.z); o.w = f2bs(f.w);
    dst[j] = o;
    return;
  }
  bx -= 8192;
  const float* in; short* out; int C, c0, r0;
  if (bx < 512)      { in = Wkv; out = Wkvt; C = 2048; c0 = (bx & 31) * 64; r0 = (bx >> 5) * 64; }
  else if (bx < 768) { bx -= 512; in = Wq; out = Wqt; C = 1024; c0 = (bx & 15) * 64; r0 = (bx >> 4) * 64; }
  else               { bx -= 768; in = Wo; out = Wot; C = 1024; c0 = (bx & 15) * 64; r0 = (bx >> 4) * 64; }
  const int tx = threadIdx.x & 63, ty = threadIdx.x >> 6;
#pragma unroll
  for (int i = 0; i < 16; ++i) {
    int r = ty + i * 4;
    tile[r][tx] = in[(size_t)(r0 + r) * C + c0 + tx];
  }
  __syncthreads();
#pragma unroll
  for (int i = 0; i < 16; ++i) {
    int r = ty + i * 4;
    out[(size_t)(c0 + r) * 1024 + r0 + tx] = f2bs(tile[tx][r]);
  }
}

// ---------------- GEMM body: 512 thr, 128x128 tile, BK=64 dbuf, 1 barrier/iter ----------------
// MODE 0: -> Q[B,H,S,64] bf16, scaled by QSCALE
// MODE 1: -> K[B,H,S,64] bf16 (even waves) and Vt[B,H,64,S] bf16 (odd waves via LDS transpose)
template <int MODE>
__device__ __forceinline__ void gemm_body8(const short* __restrict__ A, const short* __restrict__ Bt,
                                           const float* __restrict__ bias,
                                           void* __restrict__ out0, void* __restrict__ out1,
                                           int m0, int n0, int K, short* lds) {
  const int tid = threadIdx.x;
  const int w = tid >> 6, lane = tid & 63;
  const int q15 = lane & 15, quad = lane >> 4;
  const int xw = q15 & 7;
  const int wr = (w >> 1) * 32, wc = (w & 1) * 64;

  f32x4 acc[2][4];
#pragma unroll
  for (int i = 0; i < 2; ++i)
#pragma unroll
    for (int j = 0; j < 4; ++j) acc[i][j] = f32x4{0.f, 0.f, 0.f, 0.f};

  const int srow = w * 8 + (lane >> 3);        // 0..63
  const int gch  = (lane & 7) ^ (srow & 7);
  const int loff = w * 512 + lane * 8;
  const short* Ag = A + (size_t)(m0 + srow) * K + gch * 8;
  const short* Bg = Bt + (size_t)(n0 + srow) * K + gch * 8;

  GL2LDS(Ag,                  lds + loff);
  GL2LDS(Ag + (size_t)64 * K, lds + loff + 4096);
  GL2LDS(Bg,                  lds + 16384 + loff);
  GL2LDS(Bg + (size_t)64 * K, lds + 16384 + loff + 4096);

  const int NK = K >> 6;
  for (int kt = 0; kt < NK; ++kt) {
    __syncthreads();                           // cur buf DMA done; prev reads drained
    const short* Ac = lds + ((kt & 1) ? 8192 : 0);
    const short* Bc = lds + 16384 + ((kt & 1) ? 8192 : 0);
    if (kt < NK - 1) {
      const short* a2 = Ag + (kt + 1) * 64;
      const short* b2 = Bg + (kt + 1) * 64;
      short* ad = lds + ((kt & 1) ? 0 : 8192) + loff;
      short* bd = lds + 16384 + ((kt & 1) ? 0 : 8192) + loff;
      GL2LDS(a2,                  ad);
      GL2LDS(a2 + (size_t)64 * K, ad + 4096);
      GL2LDS(b2,                  bd);
      GL2LDS(b2 + (size_t)64 * K, bd + 4096);
    }
    short8 af[2][2], bf[4][2];
#pragma unroll
    for (int mi = 0; mi < 2; ++mi)
#pragma unroll
      for (int kk = 0; kk < 2; ++kk)
        af[mi][kk] = *(const short8*)(Ac + (wr + mi * 16 + q15) * 64 + (((kk * 4 + quad) ^ xw) * 8));
#pragma unroll
    for (int ni = 0; ni < 4; ++ni)
#pragma unroll
      for (int kk = 0; kk < 2; ++kk)
        bf[ni][kk] = *(const short8*)(Bc + (wc + ni * 16 + q15) * 64 + (((kk * 4 + quad) ^ xw) * 8));
#pragma unroll
    for (int mi = 0; mi < 2; ++mi)
#pragma unroll
      for (int ni = 0; ni < 4; ++ni)
#pragma unroll
        for (int kk = 0; kk < 2; ++kk)
          acc[mi][ni] = __builtin_amdgcn_mfma_f32_16x16x32_bf16(af[mi][kk], bf[ni][kk], acc[mi][ni], 0, 0, 0);
  }

  if constexpr (MODE == 0) {
#pragma unroll
    for (int mi = 0; mi < 2; ++mi)
#pragma unroll
      for (int ni = 0; ni < 4; ++ni) {
        const int n = n0 + wc + ni * 16 + q15;
        const float bn = bias[n];
#pragma unroll
        for (int r = 0; r < 4; ++r) {
          const int m = m0 + wr + mi * 16 + quad * 4 + r;
          int b = m >> 11, s = m & 2047, hh = n >> 6, d = n & 63;
          ((short*)out0)[((size_t)((b * H_ + hh) * S_ + s) << 6) + d] = f2bs((acc[mi][ni][r] + bn) * QSCALE);
        }
      }
  } else {
    const int hh = n0 >> 7;
    const int bb = m0 >> 11;
    const size_t bh = (size_t)(bb * H_ + hh);
    const int s0 = m0 & 2047;
    __syncthreads();                            // all LDS reads done; reuse lds[0..8192) as VT
    short* VT = lds;                            // [64 d][128 s], 2-short chunk swizzle ^(d&15)
    if ((w & 1) == 0) {
      // K half: cols 0..63
#pragma unroll
      for (int mi = 0; mi < 2; ++mi)
#pragma unroll
        for (int ni = 0; ni < 4; ++ni) {
          const float bn = bias[n0 + ni * 16 + q15];
#pragma unroll
          for (int r = 0; r < 4; ++r) {
            const int s = s0 + wr + mi * 16 + quad * 4 + r;
            ((short*)out0)[((bh * S_ + s) << 6) + ni * 16 + q15] = f2bs(acc[mi][ni][r] + bn);
          }
        }
    } else {
      // V half -> VT
#pragma unroll
      for (int mi = 0; mi < 2; ++mi)
#pragma unroll
        for (int ni = 0; ni < 4; ++ni) {
          const int d = ni * 16 + q15;
          const float bn = bias[n0 + 64 + d];
#pragma unroll
          for (int t = 0; t < 2; ++t) {
            const int chunk = (wr >> 1) + mi * 8 + quad * 2 + t;
            unsigned pk = pack_bf16(acc[mi][ni][2 * t] + bn, acc[mi][ni][2 * t + 1] + bn);
            *reinterpret_cast<unsigned*>(VT + d * 128 + ((chunk ^ (d & 15)) * 2)) = pk;
          }
        }
    }
    __syncthreads();
    {
      const int d = tid >> 3, t8 = tid & 7;     // 512 thr: 64 d x 8 col-groups
      unsigned vals[8];
#pragma unroll
      for (int c = 0; c < 8; ++c) {
        int chunk = t8 * 8 + c;
        vals[c] = *reinterpret_cast<unsigned*>(VT + d * 128 + ((chunk ^ (d & 15)) * 2));
      }
      uint4* dst = (uint4*)((short*)out1 + ((bh * HD_ + d) << 11) + s0 + t8 * 16);
      dst[0] = uint4{vals[0], vals[1], vals[2], vals[3]};
      dst[1] = uint4{vals[4], vals[5], vals[6], vals[7]};
    }
  }
}

// fused stage-1: blocks [0,512) -> KV proj, [512,768) -> Q proj
__global__ __launch_bounds__(512, 4)
void proj_kernel(const short* __restrict__ xb, const short* __restrict__ Wkvt,
                 const float* __restrict__ bkv, short* __restrict__ Kb, short* __restrict__ Vtb,
                 const short* __restrict__ yb, const short* __restrict__ Wqt,
                 const float* __restrict__ bq, short* __restrict__ Qb) {
  __shared__ __align__(16) short lds[32768];   // A0|A1|B0|B1, 8192 shorts each
  int bx = blockIdx.x;
  if (bx < 512)
    gemm_body8<1>(xb, Wkvt, bkv, Kb, Vtb, (bx >> 4) * 128, (bx & 15) * 128, 1024, lds);
  else {
    bx -= 512;
    gemm_body8<0>(yb, Wqt, bq, Qb, nullptr, (bx >> 3) * 128, (bx & 7) * 128, 1024, lds);
  }
}

// ---------------- O projection: 512 thr, 128x128 tile, BK=64 dbuf ----------------
__global__ __launch_bounds__(512, 4)
void gemm_o_kernel(const short* __restrict__ A, const short* __restrict__ Bt,
                   const float* __restrict__ bias, float* __restrict__ out) {
  __shared__ __align__(16) short lds[32768];
  const int tid = threadIdx.x;
  const int w = tid >> 6, lane = tid & 63;
  const int q15 = lane & 15, quad = lane >> 4;
  const int xw = q15 & 7;
  const int m0 = blockIdx.y * 128, n0 = blockIdx.x * 128;
  const int wr = (w >> 1) * 32, wc = (w & 1) * 64;

  f32x4 acc[2][4];
#pragma unroll
  for (int i = 0; i < 2; ++i)
#pragma unroll
    for (int j = 0; j < 4; ++j) acc[i][j] = f32x4{0.f, 0.f, 0.f, 0.f};

  const int srow = w * 8 + (lane >> 3);
  const int gch  = (lane & 7) ^ (srow & 7);
  const int loff = w * 512 + lane * 8;
  const short* Ag = A + (size_t)(m0 + srow) * 1024 + gch * 8;
  const short* Bg = Bt + (size_t)(n0 + srow) * 1024 + gch * 8;

  GL2LDS(Ag,             lds + loff);
  GL2LDS(Ag + 64 * 1024, lds + loff + 4096);
  GL2LDS(Bg,             lds + 16384 + loff);
  GL2LDS(Bg + 64 * 1024, lds + 16384 + loff + 4096);

  for (int kt = 0; kt < 16; ++kt) {
    __syncthreads();
    const short* Ac = lds + ((kt & 1) ? 8192 : 0);
    const short* Bc = lds + 16384 + ((kt & 1) ? 8192 : 0);
    if (kt < 15) {
      const short* a2 = Ag + (kt + 1) * 64;
      const short* b2 = Bg + (kt + 1) * 64;
      short* ad = lds + ((kt & 1) ? 0 : 8192) + loff;
      short* bd = lds + 16384 + ((kt & 1) ? 0 : 8192) + loff;
      GL2LDS(a2,             ad);
      GL2LDS(a2 + 64 * 1024, ad + 4096);
      GL2LDS(b2,             bd);
      GL2LDS(b2 + 64 * 1024, bd + 4096);
    }
    short8 af[2][2], bf[4][2];
#pragma unroll
    for (int mi = 0; mi < 2; ++mi)
#pragma unroll
      for (int kk = 0; kk < 2; ++kk)
        af[mi][kk] = *(const short8*)(Ac + (wr + mi * 16 + q15) * 64 + (((kk * 4 + quad) ^ xw) * 8));
#pragma unroll
    for (int ni = 0; ni < 4; ++ni)
#pragma unroll
      for (int kk = 0; kk < 2; ++kk)
        bf[ni][kk] = *(const short8*)(Bc + (wc + ni * 16 + q15) * 64 + (((kk * 4 + quad) ^ xw) * 8));
#pragma unroll
    for (int mi = 0; mi < 2; ++mi)
#pragma unroll
      for (int ni = 0; ni < 4; ++ni)
#pragma unroll
        for (int kk = 0; kk < 2; ++kk)
          acc[mi][ni] = __builtin_amdgcn_mfma_f32_16x16x32_bf16(af[mi][kk], bf[ni][kk], acc[mi][ni], 0, 0, 0);
  }

#pragma unroll
  for (int mi = 0; mi < 2; ++mi)
#pragma unroll
    for (int ni = 0; ni < 4; ++ni) {
      const int n = n0 + wc + ni * 16 + q15;
      const float bn = bias[n];
#pragma unroll
      for (int r = 0; r < 4; ++r) {
        const int m = m0 + wr + mi * 16 + quad * 4 + r;
        out[(size_t)m * 1024 + n] = acc[mi][ni][r] + bn;
      }
    }
}

// ---------------- flash attention: q-tile 256, 2-way key split, fused split-K combine ----------------
// grid 512 (XCD-swizzled). Writes unnormalized bf16 partial O + lsum; the LAST block of each
// (b,h,qt) pair (device-scope counter) reads both halves and writes normalized O in-place into half0.
__global__ __launch_bounds__(256, 2)
void attn_kernel(const short* __restrict__ Q, const short* __restrict__ K,
                 const short* __restrict__ Vt, short* __restrict__ Obase,
                 float* __restrict__ Ls, int* __restrict__ cnt) {
  __shared__ __align__(16) short lds[32768];   // K0|K1 (4096 ea) | V0|V1 (4096 ea) | PQ (16384)
  __shared__ int oldflag;
  short* PQ = lds + 16384;
  const int tid = threadIdx.x;
  const int w = tid >> 6, lane = tid & 63;
  const int q15 = lane & 15, quad = lane >> 4;
  const int xw = q15 & 7;
  const int bx = blockIdx.x;
  const int xcd = bx & 7, slot = bx >> 3;
  const int pg = slot >> 4, rest = slot & 15;
  const int half = rest >> 3, qt = rest & 7;
  const int pp = xcd * 4 + pg;
  const int h = pp & 15, b = pp >> 4;
  const size_t bh = (size_t)(b * H_ + h);
  const short* Qg = Q + bh * (S_ * HD_) + qt * (256 * HD_);
  const short* Kg = K + bh * (S_ * HD_);
  const short* Vg = Vt + bh * (HD_ * S_);

  const int srow = w * 8 + (lane >> 3);
  const int gch  = (lane & 7) ^ (srow & 7);
  const int loff = w * 512 + lane * 8;

  {
    const short* qg = Qg + srow * 64 + gch * 8;
#pragma unroll
    for (int t = 0; t < 8; ++t) GL2LDS(qg + t * 2048, PQ + loff + t * 2048);
  }
  const short* kg = Kg + srow * 64 + gch * 8;
  const short* vg = Vg + (size_t)srow * S_ + gch * 8;
  const int kt0 = half * 16;
  GL2LDS(kg + kt0 * 4096,          lds + loff);
  GL2LDS(kg + kt0 * 4096 + 2048,   lds + loff + 2048);
  GL2LDS(vg + kt0 * 64,                    lds + 8192 + loff);
  GL2LDS(vg + kt0 * 64 + (size_t)32 * S_,  lds + 8192 + loff + 2048);
  __syncthreads();

  short8 aq[4][2];
#pragma unroll
  for (int st = 0; st < 4; ++st)
#pragma unroll
    for (int kk = 0; kk < 2; ++kk)
      aq[st][kk] = *(const short8*)(PQ + (w * 64 + st * 16 + q15) * 64 + (((kk * 4 + quad) ^ xw) * 8));
  short* Psw = PQ + w * 4096;

  f32x4 oacc[4][4];
#pragma unroll
  for (int st = 0; st < 4; ++st)
#pragma unroll
    for (int ni = 0; ni < 4; ++ni) oacc[st][ni] = f32x4{0.f, 0.f, 0.f, 0.f};
  float lsum[4] = {0.f, 0.f, 0.f, 0.f};
  const f32x4 zz = {0.f, 0.f, 0.f, 0.f};

  for (int kt = 0; kt < 16; ++kt) {
    __syncthreads();
    const short* Kc = lds + ((kt & 1) ? 4096 : 0);
    const short* Vc = lds + 8192 + ((kt & 1) ? 4096 : 0);
    if (kt < 15) {
      const int kn = kt0 + kt + 1;
      short* kd = lds + ((kt & 1) ? 0 : 4096) + loff;
      short* vd = lds + 8192 + ((kt & 1) ? 0 : 4096) + loff;
      GL2LDS(kg + kn * 4096,          kd);
      GL2LDS(kg + kn * 4096 + 2048,   kd + 2048);
      GL2LDS(vg + kn * 64,                    vd);
      GL2LDS(vg + kn * 64 + (size_t)32 * S_,  vd + 2048);
    }

    short8 ka[4][2];
#pragma unroll
    for (int mi = 0; mi < 4; ++mi) {
      const short* kr = Kc + (mi * 16 + q15) * 64;
      ka[mi][0] = *(const short8*)(kr + ((quad ^ xw) * 8));
      ka[mi][1] = *(const short8*)(kr + (((quad + 4) ^ xw) * 8));
    }

#pragma unroll
    for (int st = 0; st < 4; ++st) {
      short* Pst = Psw + st * 1024;
#pragma unroll
      for (int mi = 0; mi < 4; ++mi) {
        f32x4 t = __builtin_amdgcn_mfma_f32_16x16x32_bf16(ka[mi][0], aq[st][0], zz, 0, 0, 0);
        f32x4 s = __builtin_amdgcn_mfma_f32_16x16x32_bf16(ka[mi][1], aq[st][1], t, 0, 0, 0);
        float p0 = fexp2(s[0]), p1 = fexp2(s[1]), p2 = fexp2(s[2]), p3 = fexp2(s[3]);
        lsum[st] += (p0 + p1) + (p2 + p3);
        uint2 pk;
        pk.x = pack_bf16(p0, p1);
        pk.y = pack_bf16(p2, p3);
        *reinterpret_cast<uint2*>(Pst + q15 * 64 + (((mi * 2 + (quad >> 1)) ^ xw) * 8) + (quad & 1) * 4) = pk;
      }
    }

    short8 ap[4][2];
#pragma unroll
    for (int st = 0; st < 4; ++st)
#pragma unroll
      for (int kk = 0; kk < 2; ++kk)
        ap[st][kk] = *(const short8*)(Psw + st * 1024 + q15 * 64 + (((kk * 4 + quad) ^ xw) * 8));
#pragma unroll
    for (int ni = 0; ni < 4; ++ni) {
      const short* vr = Vc + (ni * 16 + q15) * 64;
#pragma unroll
      for (int kk = 0; kk < 2; ++kk) {
        short8 bv = *(const short8*)(vr + (((kk * 4 + quad) ^ xw) * 8));
#pragma unroll
        for (int st = 0; st < 4; ++st)
          oacc[st][ni] = __builtin_amdgcn_mfma_f32_16x16x32_bf16(ap[st][kk], bv, oacc[st][ni], 0, 0, 0);
      }
    }
  }

  // write unnormalized partial O + lsum
  short* Op = Obase + (size_t)half * (4 << 20);
#pragma unroll
  for (int st = 0; st < 4; ++st) {
    float l = lsum[st];
    l += __shfl_xor(l, 16);
    l += __shfl_xor(l, 32);
    const int qrow = qt * 256 + w * 64 + st * 16;
    if (quad == 0)
      Ls[half * 65536 + (int)bh * 2048 + qrow + q15] = l;
#pragma unroll
    for (int ni = 0; ni < 4; ++ni) {
      const int col = h * HD_ + ni * 16 + q15;
#pragma unroll
      for (int r = 0; r < 4; ++r) {
        const int m = b * S_ + qrow + quad * 4 + r;
        Op[(size_t)m * D_ + col] = f2bs(oacc[st][ni][r]);
      }
    }
  }

  // split-K combine: last arriver of (pp,qt) merges both halves in-place into half0
  __syncthreads();                              // drain all stores (vmcnt 0 at barrier)
  if (tid == 0) {
    __threadfence();
    oldflag = atomicAdd(&cnt[pp * 8 + qt], 1);
  }
  __syncthreads();
  if (oldflag == 1) {
    __threadfence();
    const int s = qt * 256 + tid;
    const int li = (int)bh * 2048 + s;
    const float inv = frcp(Ls[li] + Ls[65536 + li]);
    const size_t base = ((size_t)(b * S_ + s) << 10) + h * HD_;
    short8* p0 = (short8*)(Obase + base);
    const short8* p1 = (const short8*)(Obase + (size_t)(4 << 20) + base);
#pragma unroll
    for (int c = 0; c < 8; ++c) {
      short8 a = p0[c], e = p1[c];
      short8 v;
#pragma unroll
      for (int i = 0; i < 8; ++i) v[i] = f2bs((bs2f(a[i]) + bs2f(e[i])) * inv);
      p0[c] = v;
    }
  }
}

extern "C" void kernel_launch(void* const* d_in, const int* in_sizes, int n_in,
                              void* d_out, int out_size, void* d_ws, size_t ws_size,
                              hipStream_t stream) {
  const float* x   = (const float*)d_in[0];
  const float* y   = (const float*)d_in[1];
  const float* Wkv = (const float*)d_in[2];
  const float* bkv = (const float*)d_in[3];
  const float* Wq  = (const float*)d_in[4];
  const float* bq  = (const float*)d_in[5];
  const float* Wo  = (const float*)d_in[6];
  const float* bo  = (const float*)d_in[7];
  float* out = (float*)d_out;

  short* xb   = (short*)d_ws;          // 4Mi shorts; reused as O_half0 then final AO
  short* yb   = xb + (4 << 20);        // 4Mi; reused as O_half1
  short* Wkvt = yb + (4 << 20);        // 2Mi
  short* Wqt  = Wkvt + (2 << 20);      // 1Mi
  short* Wot  = Wqt + (1 << 20);       // 1Mi
  short* Kb   = Wot + (1 << 20);       // 4Mi
  short* Vtb  = Kb + (4 << 20);        // 4Mi
  short* Qb   = Vtb + (4 << 20);       // 4Mi
  short* LsR  = Qb + (4 << 20);        // 4Mi region: Ls (512 KB) + cnt (1 KB)
  float* Ls   = (float*)LsR;
  int*   cnt  = (int*)(Ls + 131072);

  prep_kernel<<<9216, 256, 0, stream>>>(x, y, xb, yb, Wkv, Wkvt, Wq, Wqt, Wo, Wot, cnt);
  proj_kernel<<<768, 512, 0, stream>>>(xb, Wkvt, bkv, Kb, Vtb, yb, Wqt, bq, Qb);
  attn_kernel<<<512, 256, 0, stream>>>(Qb, Kb, Vtb, xb, Ls, cnt);
  gemm_o_kernel<<<dim3(8, 32), 512, 0, stream>>>(xb, Wot, bo, out);
}

// Round 7
// 213.374 us; speedup vs baseline: 1.1875x; 1.1875x over previous
//
#include <hip/hip_runtime.h>
#include <hip/hip_bf16.h>

typedef __attribute__((ext_vector_type(8))) short short8;
typedef __attribute__((ext_vector_type(4))) short short4v;
typedef __attribute__((ext_vector_type(4))) float f32x4;

#define B_  2
#define S_  2048
#define H_  16
#define HD_ 64
#define D_  1024
#define QSCALE 0.18033688f   /* 0.125 * log2(e): folds softmax exp2 conversion into Q proj */

__device__ __forceinline__ short f2bs(float f) {
  union { float f; unsigned u; } c; c.f = f;
  unsigned u = c.u;
  u += 0x7fffu + ((u >> 16) & 1u);   // RNE; inputs are never NaN
  return (short)(u >> 16);
}

__device__ __forceinline__ float bs2f(short v) {
  union { unsigned u; float f; } c;
  c.u = ((unsigned)(unsigned short)v) << 16;
  return c.f;
}

__device__ __forceinline__ unsigned pack_bf16(float a, float b) {
  __hip_bfloat162 h = __float22bfloat162_rn(float2{a, b});   // v_cvt_pk_bf16_f32
  return *reinterpret_cast<unsigned*>(&h);
}

__device__ __forceinline__ float fexp2(float x) {
#if __has_builtin(__builtin_amdgcn_exp2f)
  return __builtin_amdgcn_exp2f(x);
#else
  return exp2f(x);
#endif
}

__device__ __forceinline__ float frcp(float x) {
#if __has_builtin(__builtin_amdgcn_rcpf)
  return __builtin_amdgcn_rcpf(x);
#else
  return 1.0f / x;
#endif
}

#define GL2LDS(gp, lp) __builtin_amdgcn_global_load_lds( \
    (const __attribute__((address_space(1))) unsigned int*)(gp), \
    (__attribute__((address_space(3))) unsigned int*)(lp), 16, 0, 0)

// ---------------- fused prep: x/y convert + weight transposes ----------------
__global__ __launch_bounds__(256)
void prep_kernel(const float* __restrict__ x, const float* __restrict__ y,
                 short* __restrict__ xb, short* __restrict__ yb,
                 const float* __restrict__ Wkv, short* __restrict__ Wkvt,
                 const float* __restrict__ Wq, short* __restrict__ Wqt,
                 const float* __restrict__ Wo, short* __restrict__ Wot) {
  __shared__ float tile[64][65];
  int bx = blockIdx.x;
  if (bx < 8192) {
    int i = bx * 256 + threadIdx.x;
    const float4* src; short4v* dst; int j;
    if (i < (1 << 20)) { src = (const float4*)x; dst = (short4v*)xb; j = i; }
    else               { src = (const float4*)y; dst = (short4v*)yb; j = i - (1 << 20); }
    float4 f = src[j];
    short4v o;
    o.x = f2bs(f.x); o.y = f2bs(f.y); o.z = f2bs(f.z); o.w = f2bs(f.w);
    dst[j] = o;
    return;
  }
  bx -= 8192;
  const float* in; short* out; int C, c0, r0;
  if (bx < 512)      { in = Wkv; out = Wkvt; C = 2048; c0 = (bx & 31) * 64; r0 = (bx >> 5) * 64; }
  else if (bx < 768) { bx -= 512; in = Wq; out = Wqt; C = 1024; c0 = (bx & 15) * 64; r0 = (bx >> 4) * 64; }
  else               { bx -= 768; in = Wo; out = Wot; C = 1024; c0 = (bx & 15) * 64; r0 = (bx >> 4) * 64; }
  const int tx = threadIdx.x & 63, ty = threadIdx.x >> 6;
#pragma unroll
  for (int i = 0; i < 16; ++i) {
    int r = ty + i * 4;
    tile[r][tx] = in[(size_t)(r0 + r) * C + c0 + tx];
  }
  __syncthreads();
#pragma unroll
  for (int i = 0; i < 16; ++i) {
    int r = ty + i * 4;
    out[(size_t)(c0 + r) * 1024 + r0 + tx] = f2bs(tile[tx][r]);
  }
}

// ---------------- GEMM body: 512 thr, 128x128 tile, BK=64 dbuf, 1 barrier/iter ----------------
// MODE 0: -> Q[B,H,S,64] bf16, scaled by QSCALE
// MODE 1: -> K[B,H,S,64] bf16 (even waves) and Vt[B,H,64,S] bf16 (odd waves via LDS transpose)
template <int MODE>
__device__ __forceinline__ void gemm_body8(const short* __restrict__ A, const short* __restrict__ Bt,
                                           const float* __restrict__ bias,
                                           void* __restrict__ out0, void* __restrict__ out1,
                                           int m0, int n0, int K, short* lds) {
  const int tid = threadIdx.x;
  const int w = tid >> 6, lane = tid & 63;
  const int q15 = lane & 15, quad = lane >> 4;
  const int xw = q15 & 7;
  const int wr = (w >> 1) * 32, wc = (w & 1) * 64;

  f32x4 acc[2][4];
#pragma unroll
  for (int i = 0; i < 2; ++i)
#pragma unroll
    for (int j = 0; j < 4; ++j) acc[i][j] = f32x4{0.f, 0.f, 0.f, 0.f};

  const int srow = w * 8 + (lane >> 3);        // 0..63
  const int gch  = (lane & 7) ^ (srow & 7);
  const int loff = w * 512 + lane * 8;
  const short* Ag = A + (size_t)(m0 + srow) * K + gch * 8;
  const short* Bg = Bt + (size_t)(n0 + srow) * K + gch * 8;

  GL2LDS(Ag,                  lds + loff);
  GL2LDS(Ag + (size_t)64 * K, lds + loff + 4096);
  GL2LDS(Bg,                  lds + 16384 + loff);
  GL2LDS(Bg + (size_t)64 * K, lds + 16384 + loff + 4096);

  const int NK = K >> 6;
  for (int kt = 0; kt < NK; ++kt) {
    __syncthreads();                           // cur buf DMA done; prev reads drained
    const short* Ac = lds + ((kt & 1) ? 8192 : 0);
    const short* Bc = lds + 16384 + ((kt & 1) ? 8192 : 0);
    if (kt < NK - 1) {
      const short* a2 = Ag + (kt + 1) * 64;
      const short* b2 = Bg + (kt + 1) * 64;
      short* ad = lds + ((kt & 1) ? 0 : 8192) + loff;
      short* bd = lds + 16384 + ((kt & 1) ? 0 : 8192) + loff;
      GL2LDS(a2,                  ad);
      GL2LDS(a2 + (size_t)64 * K, ad + 4096);
      GL2LDS(b2,                  bd);
      GL2LDS(b2 + (size_t)64 * K, bd + 4096);
    }
    short8 af[2][2], bf[4][2];
#pragma unroll
    for (int mi = 0; mi < 2; ++mi)
#pragma unroll
      for (int kk = 0; kk < 2; ++kk)
        af[mi][kk] = *(const short8*)(Ac + (wr + mi * 16 + q15) * 64 + (((kk * 4 + quad) ^ xw) * 8));
#pragma unroll
    for (int ni = 0; ni < 4; ++ni)
#pragma unroll
      for (int kk = 0; kk < 2; ++kk)
        bf[ni][kk] = *(const short8*)(Bc + (wc + ni * 16 + q15) * 64 + (((kk * 4 + quad) ^ xw) * 8));
#pragma unroll
    for (int mi = 0; mi < 2; ++mi)
#pragma unroll
      for (int ni = 0; ni < 4; ++ni)
#pragma unroll
        for (int kk = 0; kk < 2; ++kk)
          acc[mi][ni] = __builtin_amdgcn_mfma_f32_16x16x32_bf16(af[mi][kk], bf[ni][kk], acc[mi][ni], 0, 0, 0);
  }

  if constexpr (MODE == 0) {
#pragma unroll
    for (int mi = 0; mi < 2; ++mi)
#pragma unroll
      for (int ni = 0; ni < 4; ++ni) {
        const int n = n0 + wc + ni * 16 + q15;
        const float bn = bias[n];
#pragma unroll
        for (int r = 0; r < 4; ++r) {
          const int m = m0 + wr + mi * 16 + quad * 4 + r;
          int b = m >> 11, s = m & 2047, hh = n >> 6, d = n & 63;
          ((short*)out0)[((size_t)((b * H_ + hh) * S_ + s) << 6) + d] = f2bs((acc[mi][ni][r] + bn) * QSCALE);
        }
      }
  } else {
    const int hh = n0 >> 7;
    const int bb = m0 >> 11;
    const size_t bh = (size_t)(bb * H_ + hh);
    const int s0 = m0 & 2047;
    __syncthreads();                            // all LDS reads done; reuse lds[0..8192) as VT
    short* VT = lds;                            // [64 d][128 s], 2-short chunk swizzle ^(d&15)
    if ((w & 1) == 0) {
#pragma unroll
      for (int mi = 0; mi < 2; ++mi)
#pragma unroll
        for (int ni = 0; ni < 4; ++ni) {
          const float bn = bias[n0 + ni * 16 + q15];
#pragma unroll
          for (int r = 0; r < 4; ++r) {
            const int s = s0 + wr + mi * 16 + quad * 4 + r;
            ((short*)out0)[((bh * S_ + s) << 6) + ni * 16 + q15] = f2bs(acc[mi][ni][r] + bn);
          }
        }
    } else {
#pragma unroll
      for (int mi = 0; mi < 2; ++mi)
#pragma unroll
        for (int ni = 0; ni < 4; ++ni) {
          const int d = ni * 16 + q15;
          const float bn = bias[n0 + 64 + d];
#pragma unroll
          for (int t = 0; t < 2; ++t) {
            const int chunk = (wr >> 1) + mi * 8 + quad * 2 + t;
            unsigned pk = pack_bf16(acc[mi][ni][2 * t] + bn, acc[mi][ni][2 * t + 1] + bn);
            *reinterpret_cast<unsigned*>(VT + d * 128 + ((chunk ^ (d & 15)) * 2)) = pk;
          }
        }
    }
    __syncthreads();
    {
      const int d = tid >> 3, t8 = tid & 7;     // 512 thr: 64 d x 8 col-groups
      unsigned vals[8];
#pragma unroll
      for (int c = 0; c < 8; ++c) {
        int chunk = t8 * 8 + c;
        vals[c] = *reinterpret_cast<unsigned*>(VT + d * 128 + ((chunk ^ (d & 15)) * 2));
      }
      uint4* dst = (uint4*)((short*)out1 + ((bh * HD_ + d) << 11) + s0 + t8 * 16);
      dst[0] = uint4{vals[0], vals[1], vals[2], vals[3]};
      dst[1] = uint4{vals[4], vals[5], vals[6], vals[7]};
    }
  }
}

// fused stage-1: blocks [0,512) -> KV proj, [512,768) -> Q proj
__global__ __launch_bounds__(512, 4)
void proj_kernel(const short* __restrict__ xb, const short* __restrict__ Wkvt,
                 const float* __restrict__ bkv, short* __restrict__ Kb, short* __restrict__ Vtb,
                 const short* __restrict__ yb, const short* __restrict__ Wqt,
                 const float* __restrict__ bq, short* __restrict__ Qb) {
  __shared__ __align__(16) short lds[32768];   // A0|A1|B0|B1, 8192 shorts each
  int bx = blockIdx.x;
  if (bx < 512)
    gemm_body8<1>(xb, Wkvt, bkv, Kb, Vtb, (bx >> 4) * 128, (bx & 15) * 128, 1024, lds);
  else {
    bx -= 512;
    gemm_body8<0>(yb, Wqt, bq, Qb, nullptr, (bx >> 3) * 128, (bx & 7) * 128, 1024, lds);
  }
}

// ---------------- flash attention: q-tile 256, 2-way key split (r5 structure, NO fences) ----------------
// grid 512 (XCD-swizzled). Writes UNNORMALIZED bf16 partial O + per-row lsum.
__global__ __launch_bounds__(256, 2)
void attn_kernel(const short* __restrict__ Q, const short* __restrict__ K,
                 const short* __restrict__ Vt, short* __restrict__ Obase,
                 float* __restrict__ Ls) {
  __shared__ __align__(16) short lds[32768];   // K0|K1 (4096 ea) | V0|V1 (4096 ea) | PQ (16384)
  short* PQ = lds + 16384;
  const int tid = threadIdx.x;
  const int w = tid >> 6, lane = tid & 63;
  const int q15 = lane & 15, quad = lane >> 4;
  const int xw = q15 & 7;
  const int bx = blockIdx.x;
  const int xcd = bx & 7, slot = bx >> 3;
  const int pg = slot >> 4, rest = slot & 15;
  const int half = rest >> 3, qt = rest & 7;
  const int pp = xcd * 4 + pg;
  const int h = pp & 15, b = pp >> 4;
  const size_t bh = (size_t)(b * H_ + h);
  const short* Qg = Q + bh * (S_ * HD_) + qt * (256 * HD_);
  const short* Kg = K + bh * (S_ * HD_);
  const short* Vg = Vt + bh * (HD_ * S_);

  const int srow = w * 8 + (lane >> 3);
  const int gch  = (lane & 7) ^ (srow & 7);
  const int loff = w * 512 + lane * 8;

  {
    const short* qg = Qg + srow * 64 + gch * 8;
#pragma unroll
    for (int t = 0; t < 8; ++t) GL2LDS(qg + t * 2048, PQ + loff + t * 2048);
  }
  const short* kg = Kg + srow * 64 + gch * 8;
  const short* vg = Vg + (size_t)srow * S_ + gch * 8;
  const int kt0 = half * 16;
  GL2LDS(kg + kt0 * 4096,          lds + loff);
  GL2LDS(kg + kt0 * 4096 + 2048,   lds + loff + 2048);
  GL2LDS(vg + kt0 * 64,                    lds + 8192 + loff);
  GL2LDS(vg + kt0 * 64 + (size_t)32 * S_,  lds + 8192 + loff + 2048);
  __syncthreads();

  short8 aq[4][2];
#pragma unroll
  for (int st = 0; st < 4; ++st)
#pragma unroll
    for (int kk = 0; kk < 2; ++kk)
      aq[st][kk] = *(const short8*)(PQ + (w * 64 + st * 16 + q15) * 64 + (((kk * 4 + quad) ^ xw) * 8));
  short* Psw = PQ + w * 4096;

  f32x4 oacc[4][4];
#pragma unroll
  for (int st = 0; st < 4; ++st)
#pragma unroll
    for (int ni = 0; ni < 4; ++ni) oacc[st][ni] = f32x4{0.f, 0.f, 0.f, 0.f};
  float lsum[4] = {0.f, 0.f, 0.f, 0.f};
  const f32x4 zz = {0.f, 0.f, 0.f, 0.f};

  for (int kt = 0; kt < 16; ++kt) {
    __syncthreads();
    const short* Kc = lds + ((kt & 1) ? 4096 : 0);
    const short* Vc = lds + 8192 + ((kt & 1) ? 4096 : 0);
    if (kt < 15) {
      const int kn = kt0 + kt + 1;
      short* kd = lds + ((kt & 1) ? 0 : 4096) + loff;
      short* vd = lds + 8192 + ((kt & 1) ? 0 : 4096) + loff;
      GL2LDS(kg + kn * 4096,          kd);
      GL2LDS(kg + kn * 4096 + 2048,   kd + 2048);
      GL2LDS(vg + kn * 64,                    vd);
      GL2LDS(vg + kn * 64 + (size_t)32 * S_,  vd + 2048);
    }

    short8 ka[4][2];
#pragma unroll
    for (int mi = 0; mi < 4; ++mi) {
      const short* kr = Kc + (mi * 16 + q15) * 64;
      ka[mi][0] = *(const short8*)(kr + ((quad ^ xw) * 8));
      ka[mi][1] = *(const short8*)(kr + (((quad + 4) ^ xw) * 8));
    }

#pragma unroll
    for (int st = 0; st < 4; ++st) {
      short* Pst = Psw + st * 1024;
#pragma unroll
      for (int mi = 0; mi < 4; ++mi) {
        f32x4 t = __builtin_amdgcn_mfma_f32_16x16x32_bf16(ka[mi][0], aq[st][0], zz, 0, 0, 0);
        f32x4 s = __builtin_amdgcn_mfma_f32_16x16x32_bf16(ka[mi][1], aq[st][1], t, 0, 0, 0);
        float p0 = fexp2(s[0]), p1 = fexp2(s[1]), p2 = fexp2(s[2]), p3 = fexp2(s[3]);
        lsum[st] += (p0 + p1) + (p2 + p3);
        uint2 pk;
        pk.x = pack_bf16(p0, p1);
        pk.y = pack_bf16(p2, p3);
        *reinterpret_cast<uint2*>(Pst + q15 * 64 + (((mi * 2 + (quad >> 1)) ^ xw) * 8) + (quad & 1) * 4) = pk;
      }
    }

    short8 ap[4][2];
#pragma unroll
    for (int st = 0; st < 4; ++st)
#pragma unroll
      for (int kk = 0; kk < 2; ++kk)
        ap[st][kk] = *(const short8*)(Psw + st * 1024 + q15 * 64 + (((kk * 4 + quad) ^ xw) * 8));
#pragma unroll
    for (int ni = 0; ni < 4; ++ni) {
      const short* vr = Vc + (ni * 16 + q15) * 64;
#pragma unroll
      for (int kk = 0; kk < 2; ++kk) {
        short8 bv = *(const short8*)(vr + (((kk * 4 + quad) ^ xw) * 8));
#pragma unroll
        for (int st = 0; st < 4; ++st)
          oacc[st][ni] = __builtin_amdgcn_mfma_f32_16x16x32_bf16(ap[st][kk], bv, oacc[st][ni], 0, 0, 0);
      }
    }
  }

  short* Op = Obase + (size_t)half * (4 << 20);
#pragma unroll
  for (int st = 0; st < 4; ++st) {
    float l = lsum[st];
    l += __shfl_xor(l, 16);
    l += __shfl_xor(l, 32);
    const int qrow = qt * 256 + w * 64 + st * 16;
    if (quad == 0)
      Ls[half * 65536 + (int)bh * 2048 + qrow + q15] = l;
#pragma unroll
    for (int ni = 0; ni < 4; ++ni) {
      const int col = h * HD_ + ni * 16 + q15;
#pragma unroll
      for (int r = 0; r < 4; ++r) {
        const int m = b * S_ + qrow + quad * 4 + r;
        Op[(size_t)m * D_ + col] = f2bs(oacc[st][ni][r]);
      }
    }
  }
}

// ---------------- O projection with FUSED split-K combine in A-staging ----------------
// k-tile kt == head h. A tile = (O0 + O1) * inv(lsum) computed in VGPRs -> ds_write.
__global__ __launch_bounds__(512, 4)
void gemm_o_kernel(const short* __restrict__ O0, const short* __restrict__ O1,
                   const float* __restrict__ Ls,
                   const short* __restrict__ Bt, const float* __restrict__ bias,
                   float* __restrict__ out) {
  __shared__ __align__(16) short lds[32768];   // A0|A1|B0|B1, 8192 shorts each
  const int tid = threadIdx.x;
  const int w = tid >> 6, lane = tid & 63;
  const int q15 = lane & 15, quad = lane >> 4;
  const int xw = q15 & 7;
  const int m0 = blockIdx.y * 128, n0 = blockIdx.x * 128;
  const int wr = (w >> 1) * 32, wc = (w & 1) * 64;

  f32x4 acc[2][4];
#pragma unroll
  for (int i = 0; i < 2; ++i)
#pragma unroll
    for (int j = 0; j < 4; ++j) acc[i][j] = f32x4{0.f, 0.f, 0.f, 0.f};

  const int srow = w * 8 + (lane >> 3);        // 0..63
  const int gch  = (lane & 7) ^ (srow & 7);
  const int loff = w * 512 + lane * 8;
  const int bb = m0 >> 11;
  const int s1 = (m0 & 2047) + srow;
  const short* Bg = Bt + (size_t)(n0 + srow) * 1024 + gch * 8;

  // stage tile 0: B via DMA, A via combine
  GL2LDS(Bg,             lds + 16384 + loff);
  GL2LDS(Bg + 64 * 1024, lds + 16384 + loff + 4096);
  {
    const size_t ro = (size_t)(m0 + srow) * 1024 + gch * 8;   // kt=0 -> head 0, col off 0
    short8 a0 = *(const short8*)(O0 + ro);
    short8 e0 = *(const short8*)(O1 + ro);
    short8 a1 = *(const short8*)(O0 + ro + 64 * 1024);
    short8 e1 = *(const short8*)(O1 + ro + 64 * 1024);
    const int li = bb * 16 * 2048;
    float inv0 = frcp(Ls[li + s1] + Ls[65536 + li + s1]);
    float inv1 = frcp(Ls[li + s1 + 64] + Ls[65536 + li + s1 + 64]);
    short8 v0, v1;
#pragma unroll
    for (int i = 0; i < 8; ++i) {
      v0[i] = f2bs((bs2f(a0[i]) + bs2f(e0[i])) * inv0);
      v1[i] = f2bs((bs2f(a1[i]) + bs2f(e1[i])) * inv1);
    }
    *(short8*)(lds + loff) = v0;
    *(short8*)(lds + loff + 4096) = v1;
  }

  for (int kt = 0; kt < 16; ++kt) {
    __syncthreads();                           // cur buf ready (DMA + ds_writes drained)
    const short* Ac = lds + ((kt & 1) ? 8192 : 0);
    const short* Bc = lds + 16384 + ((kt & 1) ? 8192 : 0);

    // prefetch next tile: issue loads now, combine after MFMAs
    short8 a0, e0, a1, e1;
    float L00, L01, L10, L11;
    if (kt < 15) {
      const size_t ro = (size_t)(m0 + srow) * 1024 + (kt + 1) * 64 + gch * 8;
      a0 = *(const short8*)(O0 + ro);
      e0 = *(const short8*)(O1 + ro);
      a1 = *(const short8*)(O0 + ro + 64 * 1024);
      e1 = *(const short8*)(O1 + ro + 64 * 1024);
      const int li = (bb * 16 + kt + 1) * 2048;
      L00 = Ls[li + s1];      L01 = Ls[65536 + li + s1];
      L10 = Ls[li + s1 + 64]; L11 = Ls[65536 + li + s1 + 64];
      const short* b2 = Bg + (kt + 1) * 64;
      short* bd = lds + 16384 + ((kt & 1) ? 0 : 8192) + loff;
      GL2LDS(b2,             bd);
      GL2LDS(b2 + 64 * 1024, bd + 4096);
    }

    short8 af[2][2], bf[4][2];
#pragma unroll
    for (int mi = 0; mi < 2; ++mi)
#pragma unroll
      for (int kk = 0; kk < 2; ++kk)
        af[mi][kk] = *(const short8*)(Ac + (wr + mi * 16 + q15) * 64 + (((kk * 4 + quad) ^ xw) * 8));
#pragma unroll
    for (int ni = 0; ni < 4; ++ni)
#pragma unroll
      for (int kk = 0; kk < 2; ++kk)
        bf[ni][kk] = *(const short8*)(Bc + (wc + ni * 16 + q15) * 64 + (((kk * 4 + quad) ^ xw) * 8));
#pragma unroll
    for (int mi = 0; mi < 2; ++mi)
#pragma unroll
      for (int ni = 0; ni < 4; ++ni)
#pragma unroll
        for (int kk = 0; kk < 2; ++kk)
          acc[mi][ni] = __builtin_amdgcn_mfma_f32_16x16x32_bf16(af[mi][kk], bf[ni][kk], acc[mi][ni], 0, 0, 0);

    if (kt < 15) {
      float inv0 = frcp(L00 + L01);
      float inv1 = frcp(L10 + L11);
      short8 v0, v1;
#pragma unroll
      for (int i = 0; i < 8; ++i) {
        v0[i] = f2bs((bs2f(a0[i]) + bs2f(e0[i])) * inv0);
        v1[i] = f2bs((bs2f(a1[i]) + bs2f(e1[i])) * inv1);
      }
      short* ad = lds + ((kt & 1) ? 0 : 8192) + loff;
      *(short8*)(ad) = v0;
      *(short8*)(ad + 4096) = v1;
    }
  }

#pragma unroll
  for (int mi = 0; mi < 2; ++mi)
#pragma unroll
    for (int ni = 0; ni < 4; ++ni) {
      const int n = n0 + wc + ni * 16 + q15;
      const float bn = bias[n];
#pragma unroll
      for (int r = 0; r < 4; ++r) {
        const int m = m0 + wr + mi * 16 + quad * 4 + r;
        out[(size_t)m * 1024 + n] = acc[mi][ni][r] + bn;
      }
    }
}

extern "C" void kernel_launch(void* const* d_in, const int* in_sizes, int n_in,
                              void* d_out, int out_size, void* d_ws, size_t ws_size,
                              hipStream_t stream) {
  const float* x   = (const float*)d_in[0];
  const float* y   = (const float*)d_in[1];
  const float* Wkv = (const float*)d_in[2];
  const float* bkv = (const float*)d_in[3];
  const float* Wq  = (const float*)d_in[4];
  const float* bq  = (const float*)d_in[5];
  const float* Wo  = (const float*)d_in[6];
  const float* bo  = (const float*)d_in[7];
  float* out = (float*)d_out;

  short* xb   = (short*)d_ws;          // 4Mi shorts; reused as O_half0 after proj
  short* yb   = xb + (4 << 20);        // 4Mi; reused as O_half1 after proj
  short* Wkvt = yb + (4 << 20);        // 2Mi shorts = 4MB
  short* Wqt  = Wkvt + (2 << 20);      // 1Mi
  short* Wot  = Wqt + (1 << 20);       // 1Mi
  short* Kb   = Wot + (1 << 20);       // 4Mi
  short* Vtb  = Kb + (4 << 20);        // 4Mi
  short* Qb   = Vtb + (4 << 20);       // 4Mi
  short* LsR  = Qb + (4 << 20);        // Ls: 2 x 65536 floats = 512 KB
  float* Ls   = (float*)LsR;

  prep_kernel<<<9216, 256, 0, stream>>>(x, y, xb, yb, Wkv, Wkvt, Wq, Wqt, Wo, Wot);
  proj_kernel<<<768, 512, 0, stream>>>(xb, Wkvt, bkv, Kb, Vtb, yb, Wqt, bq, Qb);
  attn_kernel<<<512, 256, 0, stream>>>(Qb, Kb, Vtb, xb, Ls);
  gemm_o_kernel<<<dim3(8, 32), 512, 0, stream>>>(xb, yb, Ls, Wot, bo, out);
}

// Round 8
// 212.043 us; speedup vs baseline: 1.1949x; 1.0063x over previous
//
#include <hip/hip_runtime.h>
#include <hip/hip_bf16.h>

typedef __attribute__((ext_vector_type(8))) short short8;
typedef __attribute__((ext_vector_type(4))) short short4v;
typedef __attribute__((ext_vector_type(4))) float f32x4;

#define B_  2
#define S_  2048
#define H_  16
#define HD_ 64
#define D_  1024
#define QSCALE 0.18033688f   /* 0.125 * log2(e): folds softmax exp2 conversion into Q proj */

__device__ __forceinline__ short f2bs(float f) {
  union { float f; unsigned u; } c; c.f = f;
  unsigned u = c.u;
  u += 0x7fffu + ((u >> 16) & 1u);   // RNE; inputs are never NaN
  return (short)(u >> 16);
}

__device__ __forceinline__ float bs2f(short v) {
  union { unsigned u; float f; } c;
  c.u = ((unsigned)(unsigned short)v) << 16;
  return c.f;
}

__device__ __forceinline__ unsigned pack_bf16(float a, float b) {
  __hip_bfloat162 h = __float22bfloat162_rn(float2{a, b});   // v_cvt_pk_bf16_f32
  return *reinterpret_cast<unsigned*>(&h);
}

__device__ __forceinline__ float fexp2(float x) {
#if __has_builtin(__builtin_amdgcn_exp2f)
  return __builtin_amdgcn_exp2f(x);
#else
  return exp2f(x);
#endif
}

__device__ __forceinline__ float frcp(float x) {
#if __has_builtin(__builtin_amdgcn_rcpf)
  return __builtin_amdgcn_rcpf(x);
#else
  return 1.0f / x;
#endif
}

#define GL2LDS(gp, lp) __builtin_amdgcn_global_load_lds( \
    (const __attribute__((address_space(1))) unsigned int*)(gp), \
    (__attribute__((address_space(3))) unsigned int*)(lp), 16, 0, 0)

// ---------------- fused prep: x/y convert + weight transposes ----------------
__global__ __launch_bounds__(256)
void prep_kernel(const float* __restrict__ x, const float* __restrict__ y,
                 short* __restrict__ xb, short* __restrict__ yb,
                 const float* __restrict__ Wkv, short* __restrict__ Wkvt,
                 const float* __restrict__ Wq, short* __restrict__ Wqt,
                 const float* __restrict__ Wo, short* __restrict__ Wot) {
  __shared__ float tile[64][65];
  int bx = blockIdx.x;
  if (bx < 8192) {
    int i = bx * 256 + threadIdx.x;
    const float4* src; short4v* dst; int j;
    if (i < (1 << 20)) { src = (const float4*)x; dst = (short4v*)xb; j = i; }
    else               { src = (const float4*)y; dst = (short4v*)yb; j = i - (1 << 20); }
    float4 f = src[j];
    short4v o;
    o.x = f2bs(f.x); o.y = f2bs(f.y); o.z = f2bs(f.z); o.w = f2bs(f.w);
    dst[j] = o;
    return;
  }
  bx -= 8192;
  const float* in; short* out; int C, c0, r0;
  if (bx < 512)      { in = Wkv; out = Wkvt; C = 2048; c0 = (bx & 31) * 64; r0 = (bx >> 5) * 64; }
  else if (bx < 768) { bx -= 512; in = Wq; out = Wqt; C = 1024; c0 = (bx & 15) * 64; r0 = (bx >> 4) * 64; }
  else               { bx -= 768; in = Wo; out = Wot; C = 1024; c0 = (bx & 15) * 64; r0 = (bx >> 4) * 64; }
  const int tx = threadIdx.x & 63, ty = threadIdx.x >> 6;
#pragma unroll
  for (int i = 0; i < 16; ++i) {
    int r = ty + i * 4;
    tile[r][tx] = in[(size_t)(r0 + r) * C + c0 + tx];
  }
  __syncthreads();
#pragma unroll
  for (int i = 0; i < 16; ++i) {
    int r = ty + i * 4;
    out[(size_t)(c0 + r) * 1024 + r0 + tx] = f2bs(tile[tx][r]);
  }
}

// ---------------- GEMM body: 512 thr, 128x128 tile, BK=64 dbuf, 1 barrier/iter ----------------
// MODE 0: -> Q[B,H,S,64] bf16, scaled by QSCALE
// MODE 1: -> K[B,H,S,64] bf16 (even waves) and Vt[B,H,64,S] bf16 (odd waves via LDS transpose)
template <int MODE>
__device__ __forceinline__ void gemm_body8(const short* __restrict__ A, const short* __restrict__ Bt,
                                           const float* __restrict__ bias,
                                           void* __restrict__ out0, void* __restrict__ out1,
                                           int m0, int n0, int K, short* lds) {
  const int tid = threadIdx.x;
  const int w = tid >> 6, lane = tid & 63;
  const int q15 = lane & 15, quad = lane >> 4;
  const int xw = q15 & 7;
  const int wr = (w >> 1) * 32, wc = (w & 1) * 64;

  f32x4 acc[2][4];
#pragma unroll
  for (int i = 0; i < 2; ++i)
#pragma unroll
    for (int j = 0; j < 4; ++j) acc[i][j] = f32x4{0.f, 0.f, 0.f, 0.f};

  const int srow = w * 8 + (lane >> 3);        // 0..63
  const int gch  = (lane & 7) ^ (srow & 7);
  const int loff = w * 512 + lane * 8;
  const short* Ag = A + (size_t)(m0 + srow) * K + gch * 8;
  const short* Bg = Bt + (size_t)(n0 + srow) * K + gch * 8;

  GL2LDS(Ag,                  lds + loff);
  GL2LDS(Ag + (size_t)64 * K, lds + loff + 4096);
  GL2LDS(Bg,                  lds + 16384 + loff);
  GL2LDS(Bg + (size_t)64 * K, lds + 16384 + loff + 4096);

  const int NK = K >> 6;
  for (int kt = 0; kt < NK; ++kt) {
    __syncthreads();                           // cur buf DMA done; prev reads drained
    const short* Ac = lds + ((kt & 1) ? 8192 : 0);
    const short* Bc = lds + 16384 + ((kt & 1) ? 8192 : 0);
    if (kt < NK - 1) {
      const short* a2 = Ag + (kt + 1) * 64;
      const short* b2 = Bg + (kt + 1) * 64;
      short* ad = lds + ((kt & 1) ? 0 : 8192) + loff;
      short* bd = lds + 16384 + ((kt & 1) ? 0 : 8192) + loff;
      GL2LDS(a2,                  ad);
      GL2LDS(a2 + (size_t)64 * K, ad + 4096);
      GL2LDS(b2,                  bd);
      GL2LDS(b2 + (size_t)64 * K, bd + 4096);
    }
    short8 af[2][2], bf[4][2];
#pragma unroll
    for (int mi = 0; mi < 2; ++mi)
#pragma unroll
      for (int kk = 0; kk < 2; ++kk)
        af[mi][kk] = *(const short8*)(Ac + (wr + mi * 16 + q15) * 64 + (((kk * 4 + quad) ^ xw) * 8));
#pragma unroll
    for (int ni = 0; ni < 4; ++ni)
#pragma unroll
      for (int kk = 0; kk < 2; ++kk)
        bf[ni][kk] = *(const short8*)(Bc + (wc + ni * 16 + q15) * 64 + (((kk * 4 + quad) ^ xw) * 8));
#pragma unroll
    for (int mi = 0; mi < 2; ++mi)
#pragma unroll
      for (int ni = 0; ni < 4; ++ni)
#pragma unroll
        for (int kk = 0; kk < 2; ++kk)
          acc[mi][ni] = __builtin_amdgcn_mfma_f32_16x16x32_bf16(af[mi][kk], bf[ni][kk], acc[mi][ni], 0, 0, 0);
  }

  if constexpr (MODE == 0) {
#pragma unroll
    for (int mi = 0; mi < 2; ++mi)
#pragma unroll
      for (int ni = 0; ni < 4; ++ni) {
        const int n = n0 + wc + ni * 16 + q15;
        const float bn = bias[n];
#pragma unroll
        for (int r = 0; r < 4; ++r) {
          const int m = m0 + wr + mi * 16 + quad * 4 + r;
          int b = m >> 11, s = m & 2047, hh = n >> 6, d = n & 63;
          ((short*)out0)[((size_t)((b * H_ + hh) * S_ + s) << 6) + d] = f2bs((acc[mi][ni][r] + bn) * QSCALE);
        }
      }
  } else {
    const int hh = n0 >> 7;
    const int bb = m0 >> 11;
    const size_t bh = (size_t)(bb * H_ + hh);
    const int s0 = m0 & 2047;
    __syncthreads();                            // all LDS reads done; reuse lds[0..8192) as VT
    short* VT = lds;                            // [64 d][128 s], 2-short chunk swizzle ^(d&15)
    if ((w & 1) == 0) {
#pragma unroll
      for (int mi = 0; mi < 2; ++mi)
#pragma unroll
        for (int ni = 0; ni < 4; ++ni) {
          const float bn = bias[n0 + ni * 16 + q15];
#pragma unroll
          for (int r = 0; r < 4; ++r) {
            const int s = s0 + wr + mi * 16 + quad * 4 + r;
            ((short*)out0)[((bh * S_ + s) << 6) + ni * 16 + q15] = f2bs(acc[mi][ni][r] + bn);
          }
        }
    } else {
#pragma unroll
      for (int mi = 0; mi < 2; ++mi)
#pragma unroll
        for (int ni = 0; ni < 4; ++ni) {
          const int d = ni * 16 + q15;
          const float bn = bias[n0 + 64 + d];
#pragma unroll
          for (int t = 0; t < 2; ++t) {
            const int chunk = (wr >> 1) + mi * 8 + quad * 2 + t;
            unsigned pk = pack_bf16(acc[mi][ni][2 * t] + bn, acc[mi][ni][2 * t + 1] + bn);
            *reinterpret_cast<unsigned*>(VT + d * 128 + ((chunk ^ (d & 15)) * 2)) = pk;
          }
        }
    }
    __syncthreads();
    {
      const int d = tid >> 3, t8 = tid & 7;     // 512 thr: 64 d x 8 col-groups
      unsigned vals[8];
#pragma unroll
      for (int c = 0; c < 8; ++c) {
        int chunk = t8 * 8 + c;
        vals[c] = *reinterpret_cast<unsigned*>(VT + d * 128 + ((chunk ^ (d & 15)) * 2));
      }
      uint4* dst = (uint4*)((short*)out1 + ((bh * HD_ + d) << 11) + s0 + t8 * 16);
      dst[0] = uint4{vals[0], vals[1], vals[2], vals[3]};
      dst[1] = uint4{vals[4], vals[5], vals[6], vals[7]};
    }
  }
}

// fused stage-1: blocks [0,512) -> KV proj, [512,768) -> Q proj
__global__ __launch_bounds__(512, 4)
void proj_kernel(const short* __restrict__ xb, const short* __restrict__ Wkvt,
                 const float* __restrict__ bkv, short* __restrict__ Kb, short* __restrict__ Vtb,
                 const short* __restrict__ yb, const short* __restrict__ Wqt,
                 const float* __restrict__ bq, short* __restrict__ Qb) {
  __shared__ __align__(16) short lds[32768];   // A0|A1|B0|B1, 8192 shorts each
  int bx = blockIdx.x;
  if (bx < 512)
    gemm_body8<1>(xb, Wkvt, bkv, Kb, Vtb, (bx >> 4) * 128, (bx & 15) * 128, 1024, lds);
  else {
    bx -= 512;
    gemm_body8<0>(yb, Wqt, bq, Qb, nullptr, (bx >> 3) * 128, (bx & 7) * 128, 1024, lds);
  }
}

// ---------------- flash attention: q-tile 128 (2 strips/wave), seq-P, 40KB LDS ----------------
// grid 1024 (XCD-swizzled): 32 bh x 16 qt x 2 key-halves. 12 waves/CU (3 blocks).
// Writes UNNORMALIZED bf16 partial O + per-row lsum. Q pre-scaled by 0.125*log2e.
__global__ __launch_bounds__(256, 3)
void attn_kernel(const short* __restrict__ Q, const short* __restrict__ K,
                 const short* __restrict__ Vt, short* __restrict__ O0,
                 short* __restrict__ O1, float* __restrict__ Ls) {
  // LDS 40KB: K0[0,4096) K1[4096,8192) V0[8192,12288) V1[12288,16384) P[16384,20480)
  // Q (128x64 = 8192 shorts) staged transiently over [0,8192) before the K-loop.
  __shared__ __align__(16) short lds[20480];
  const int tid = threadIdx.x;
  const int w = tid >> 6, lane = tid & 63;
  const int q15 = lane & 15, quad = lane >> 4;
  const int xw = q15 & 7;
  const int bx = blockIdx.x;
  const int xcd = bx & 7, slot = bx >> 3;       // 128 slots per XCD
  const int pg = slot >> 5, rest = slot & 31;   // 4 (b,h) pairs per XCD
  const int half = rest >> 4, qt = rest & 15;   // 2 key-halves x 16 q-tiles of 128
  const int pp = xcd * 4 + pg;
  const int h = pp & 15, b = pp >> 4;
  const size_t bh = (size_t)(b * H_ + h);
  const short* Qg = Q + bh * (S_ * HD_) + qt * (128 * HD_);
  const short* Kg = K + bh * (S_ * HD_);
  const short* Vg = Vt + bh * (HD_ * S_);

  const int srow = w * 8 + (lane >> 3);         // 0..31
  const int gch  = (lane & 7) ^ (srow & 7);
  const int loff = w * 512 + lane * 8;

  // stage Q (128 rows = 4 rounds of 32) into lds[0,8192)
  {
    const short* qg = Qg + srow * 64 + gch * 8;
#pragma unroll
    for (int t = 0; t < 4; ++t) GL2LDS(qg + t * 2048, lds + loff + t * 2048);
  }
  __syncthreads();                              // Q DMA done
  short8 aq[2][2];                              // 2 strips of 16 q-rows
#pragma unroll
  for (int st = 0; st < 2; ++st)
#pragma unroll
    for (int kk = 0; kk < 2; ++kk)
      aq[st][kk] = *(const short8*)(lds + (w * 32 + st * 16 + q15) * 64 + (((kk * 4 + quad) ^ xw) * 8));
  __syncthreads();                              // all Q reads done before K/V overwrite

  const short* kg = Kg + srow * 64 + gch * 8;
  const short* vg = Vg + (size_t)srow * S_ + gch * 8;
  const int kt0 = half * 16;
  GL2LDS(kg + kt0 * 4096,          lds + loff);
  GL2LDS(kg + kt0 * 4096 + 2048,   lds + loff + 2048);
  GL2LDS(vg + kt0 * 64,                    lds + 8192 + loff);
  GL2LDS(vg + kt0 * 64 + (size_t)32 * S_,  lds + 8192 + loff + 2048);

  short* Pw = lds + 16384 + w * 1024;           // per-wave P[16 q][64 s], reused per strip

  f32x4 oacc[2][4];
#pragma unroll
  for (int st = 0; st < 2; ++st)
#pragma unroll
    for (int ni = 0; ni < 4; ++ni) oacc[st][ni] = f32x4{0.f, 0.f, 0.f, 0.f};
  float lsum[2] = {0.f, 0.f};
  const f32x4 zz = {0.f, 0.f, 0.f, 0.f};

  for (int kt = 0; kt < 16; ++kt) {
    __syncthreads();                            // cur buf DMA done; all waves past prev reads
    const short* Kc = lds + ((kt & 1) ? 4096 : 0);
    const short* Vc = lds + 8192 + ((kt & 1) ? 4096 : 0);
    if (kt < 15) {
      const int kn = kt0 + kt + 1;
      short* kd = lds + ((kt & 1) ? 0 : 4096) + loff;
      short* vd = lds + 8192 + ((kt & 1) ? 0 : 4096) + loff;
      GL2LDS(kg + kn * 4096,          kd);
      GL2LDS(kg + kn * 4096 + 2048,   kd + 2048);
      GL2LDS(vg + kn * 64,                    vd);
      GL2LDS(vg + kn * 64 + (size_t)32 * S_,  vd + 2048);
    }

    // K and V fragments once per iter, reused by both strips
    short8 ka[4][2], bv[4][2];
#pragma unroll
    for (int mi = 0; mi < 4; ++mi) {
      const short* kr = Kc + (mi * 16 + q15) * 64;
      ka[mi][0] = *(const short8*)(kr + ((quad ^ xw) * 8));
      ka[mi][1] = *(const short8*)(kr + (((quad + 4) ^ xw) * 8));
      const short* vr = Vc + (mi * 16 + q15) * 64;
      bv[mi][0] = *(const short8*)(vr + ((quad ^ xw) * 8));
      bv[mi][1] = *(const short8*)(vr + (((quad + 4) ^ xw) * 8));
    }

#pragma unroll
    for (int st = 0; st < 2; ++st) {
      // S^T = K Q^T -> exp2 -> pack -> per-wave P (same buffer each strip; same-wave DS order)
#pragma unroll
      for (int mi = 0; mi < 4; ++mi) {
        f32x4 t = __builtin_amdgcn_mfma_f32_16x16x32_bf16(ka[mi][0], aq[st][0], zz, 0, 0, 0);
        f32x4 s = __builtin_amdgcn_mfma_f32_16x16x32_bf16(ka[mi][1], aq[st][1], t, 0, 0, 0);
        float p0 = fexp2(s[0]), p1 = fexp2(s[1]), p2 = fexp2(s[2]), p3 = fexp2(s[3]);
        lsum[st] += (p0 + p1) + (p2 + p3);
        uint2 pk;
        pk.x = pack_bf16(p0, p1);
        pk.y = pack_bf16(p2, p3);
        *reinterpret_cast<uint2*>(Pw + q15 * 64 + (((mi * 2 + (quad >> 1)) ^ xw) * 8) + (quad & 1) * 4) = pk;
      }
      short8 ap[2];
#pragma unroll
      for (int kk = 0; kk < 2; ++kk)
        ap[kk] = *(const short8*)(Pw + q15 * 64 + (((kk * 4 + quad) ^ xw) * 8));
#pragma unroll
      for (int ni = 0; ni < 4; ++ni)
#pragma unroll
        for (int kk = 0; kk < 2; ++kk)
          oacc[st][ni] = __builtin_amdgcn_mfma_f32_16x16x32_bf16(ap[kk], bv[ni][kk], oacc[st][ni], 0, 0, 0);
    }
  }

  // epilogue: unnormalized partial O (bf16) + lsum
  short* Op = half ? O1 : O0;
#pragma unroll
  for (int st = 0; st < 2; ++st) {
    float l = lsum[st];
    l += __shfl_xor(l, 16);
    l += __shfl_xor(l, 32);
    const int qrow = qt * 128 + w * 32 + st * 16;
    if (quad == 0)
      Ls[half * 65536 + (int)bh * 2048 + qrow + q15] = l;
#pragma unroll
    for (int ni = 0; ni < 4; ++ni) {
      const int col = h * HD_ + ni * 16 + q15;
#pragma unroll
      for (int r = 0; r < 4; ++r) {
        const int m = b * S_ + qrow + quad * 4 + r;
        Op[(size_t)m * D_ + col] = f2bs(oacc[st][ni][r]);
      }
    }
  }
}

// ---------------- O projection: 64x128 tile, grid 512 (2 blocks/CU), fused split-K combine ----------------
// k-tile kt == head. A tile = (O0 + O1) * inv(lsum) computed in VGPRs -> ds_write.
__global__ __launch_bounds__(512, 4)
void gemm_o_kernel(const short* __restrict__ O0, const short* __restrict__ O1,
                   const float* __restrict__ Ls,
                   const short* __restrict__ Bt, const float* __restrict__ bias,
                   float* __restrict__ out) {
  __shared__ __align__(16) short lds[24576];   // A0[0,4096) A1[4096,8192) B0[8192,16384) B1[16384,24576)
  const int tid = threadIdx.x;
  const int w = tid >> 6, lane = tid & 63;
  const int q15 = lane & 15, quad = lane >> 4;
  const int xw = q15 & 7;
  const int m0 = blockIdx.y * 64, n0 = blockIdx.x * 128;
  const int wr = (w >> 1) * 16, wc = (w & 1) * 64;   // 8 waves: 4x16 m, 2x64 n

  f32x4 acc[4];
#pragma unroll
  for (int j = 0; j < 4; ++j) acc[j] = f32x4{0.f, 0.f, 0.f, 0.f};

  // A combine mapping: 512 thr cover 64 rows x 8 chunks
  const int rowA = tid >> 3, s8 = tid & 7;
  const int gchA = s8 ^ (rowA & 7);
  const int bb = m0 >> 11;
  const int s1 = (m0 & 2047) + rowA;
  // B staging mapping
  const int srow = w * 8 + (lane >> 3);        // 0..63
  const int gchB = (lane & 7) ^ (srow & 7);
  const int loff = w * 512 + lane * 8;
  const short* Bg = Bt + (size_t)(n0 + srow) * 1024 + gchB * 8;

  // stage tile 0: B via DMA, A via combine
  GL2LDS(Bg,             lds + 8192 + loff);
  GL2LDS(Bg + 64 * 1024, lds + 8192 + loff + 4096);
  {
    const size_t ro = (size_t)(m0 + rowA) * 1024 + gchA * 8;
    short8 a0 = *(const short8*)(O0 + ro);
    short8 e0 = *(const short8*)(O1 + ro);
    const int li = bb * 16 * 2048 + s1;
    float inv = frcp(Ls[li] + Ls[65536 + li]);
    short8 v;
#pragma unroll
    for (int i = 0; i < 8; ++i) v[i] = f2bs((bs2f(a0[i]) + bs2f(e0[i])) * inv);
    *(short8*)(lds + rowA * 64 + s8 * 8) = v;
  }

  for (int kt = 0; kt < 16; ++kt) {
    __syncthreads();                           // cur buf ready (DMA + ds_writes drained)
    const short* Ac = lds + ((kt & 1) ? 4096 : 0);
    const short* Bc = lds + 8192 + ((kt & 1) ? 8192 : 0);

    short8 a0, e0;
    float L0, L1;
    if (kt < 15) {
      const size_t ro = (size_t)(m0 + rowA) * 1024 + (kt + 1) * 64 + gchA * 8;
      a0 = *(const short8*)(O0 + ro);
      e0 = *(const short8*)(O1 + ro);
      const int li = (bb * 16 + kt + 1) * 2048 + s1;
      L0 = Ls[li]; L1 = Ls[65536 + li];
      const short* b2 = Bg + (kt + 1) * 64;
      short* bd = lds + 8192 + ((kt & 1) ? 0 : 8192) + loff;
      GL2LDS(b2,             bd);
      GL2LDS(b2 + 64 * 1024, bd + 4096);
    }

    short8 af[2], bf[4][2];
#pragma unroll
    for (int kk = 0; kk < 2; ++kk)
      af[kk] = *(const short8*)(Ac + (wr + q15) * 64 + (((kk * 4 + quad) ^ xw) * 8));
#pragma unroll
    for (int ni = 0; ni < 4; ++ni)
#pragma unroll
      for (int kk = 0; kk < 2; ++kk)
        bf[ni][kk] = *(const short8*)(Bc + (wc + ni * 16 + q15) * 64 + (((kk * 4 + quad) ^ xw) * 8));
#pragma unroll
    for (int ni = 0; ni < 4; ++ni)
#pragma unroll
      for (int kk = 0; kk < 2; ++kk)
        acc[ni] = __builtin_amdgcn_mfma_f32_16x16x32_bf16(af[kk], bf[ni][kk], acc[ni], 0, 0, 0);

    if (kt < 15) {
      float inv = frcp(L0 + L1);
      short8 v;
#pragma unroll
      for (int i = 0; i < 8; ++i) v[i] = f2bs((bs2f(a0[i]) + bs2f(e0[i])) * inv);
      *(short8*)(lds + ((kt & 1) ? 0 : 4096) + rowA * 64 + s8 * 8) = v;
    }
  }

#pragma unroll
  for (int ni = 0; ni < 4; ++ni) {
    const int n = n0 + wc + ni * 16 + q15;
    const float bn = bias[n];
#pragma unroll
    for (int r = 0; r < 4; ++r) {
      const int m = m0 + wr + quad * 4 + r;
      out[(size_t)m * 1024 + n] = acc[ni][r] + bn;
    }
  }
}

extern "C" void kernel_launch(void* const* d_in, const int* in_sizes, int n_in,
                              void* d_out, int out_size, void* d_ws, size_t ws_size,
                              hipStream_t stream) {
  const float* x   = (const float*)d_in[0];
  const float* y   = (const float*)d_in[1];
  const float* Wkv = (const float*)d_in[2];
  const float* bkv = (const float*)d_in[3];
  const float* Wq  = (const float*)d_in[4];
  const float* bq  = (const float*)d_in[5];
  const float* Wo  = (const float*)d_in[6];
  const float* bo  = (const float*)d_in[7];
  float* out = (float*)d_out;

  short* xb   = (short*)d_ws;          // 4Mi shorts; reused as O_half0 after proj
  short* yb   = xb + (4 << 20);        // 4Mi; reused as O_half1 after proj
  short* Wkvt = yb + (4 << 20);        // 2Mi
  short* Wqt  = Wkvt + (2 << 20);      // 1Mi
  short* Wot  = Wqt + (1 << 20);       // 1Mi
  short* Kb   = Wot + (1 << 20);       // 4Mi
  short* Vtb  = Kb + (4 << 20);        // 4Mi
  short* Qb   = Vtb + (4 << 20);       // 4Mi
  short* LsR  = Qb + (4 << 20);        // Ls: 2 x 65536 floats = 512 KB
  float* Ls   = (float*)LsR;

  prep_kernel<<<9216, 256, 0, stream>>>(x, y, xb, yb, Wkv, Wkvt, Wq, Wqt, Wo, Wot);
  proj_kernel<<<768, 512, 0, stream>>>(xb, Wkvt, bkv, Kb, Vtb, yb, Wqt, bq, Qb);
  attn_kernel<<<1024, 256, 0, stream>>>(Qb, Kb, Vtb, xb, yb, Ls);
  gemm_o_kernel<<<dim3(8, 64), 512, 0, stream>>>(xb, yb, Ls, Wot, bo, out);
}